// Round 10
// baseline (169.382 us; speedup 1.0000x reference)
//
#include <hip/hip_runtime.h>
#include <hip/hip_cooperative_groups.h>
#include <math.h>

namespace cg = cooperative_groups;

#define NN 4096
#define HH 480
#define WW 640
#define RAD2 4.0f
#define TH_SCORE 0.1f
#define KPPEN -0.001f
#define CXN 160
#define CYN 120
#define NCELL (CXN * CYN)
#define SLOTS 8
#define CAP 48
#define NBLK 128

// ---------------- workspace layout (bytes) ----------------
#define OFF_SCORES  0        // f32 [8][4096]               131072
#define OFF_PTS     131072   // float4 [8][4096]            524288
#define OFF_CNT     655360   // u8  [8][4096]               32768
#define OFF_PARTNER 688128   // u16 [8][4096]               65536
#define OFF_ROWS    753664   // uint4 [8][4096] (8xu16)     524288
#define OFF_CELLS   1277952  // u16 [8][19200][8]           2457600
#define OFF_CCNT    3735552  // u32 [8][19200]              614400
#define OFF_ACC     4349952  // f32 [2][4]                  32
// memset per call: [OFF_CCNT, OFF_ACC+32) = 614432 bytes (contiguous)

__global__ __launch_bounds__(256) void k_fused(
    const float* __restrict__ lp0, const float* __restrict__ lp1,
    const float* __restrict__ kp0, const float* __restrict__ kp1,
    const float* __restrict__ dd0, const float* __restrict__ dd1,
    float* __restrict__ scores, float4* __restrict__ pts,
    unsigned char* __restrict__ cnt, unsigned short* __restrict__ partner,
    uint4* __restrict__ rows4, unsigned short* __restrict__ cells,
    unsigned int* __restrict__ ccnt, float* __restrict__ acc,
    float* __restrict__ out)
{
#pragma clang fp contract(off)
    __shared__ float          s_sc[NN];          // 16 KB
    __shared__ unsigned char  s_cnt[NN];         // 4 KB
    __shared__ unsigned short s_partner[NN];     // 8 KB
    __shared__ unsigned short s_mem[256][CAP + 2];  // 25.6 KB (pad 25 words)
    __shared__ float s_red[4];

    cg::grid_group grid = cg::this_grid();
    int tid = threadIdx.x;
    int gid = blockIdx.x * 256 + tid;            // 0..32767, 1 thread/point

    // ================= phase A: sample + bin =================
    {
        int s = gid >> 14;
        int r = gid & 16383;
        int b = r >> 12;
        const float* kp  = (s ? kp1 : kp0) + (size_t)r * 2;
        const float* img = (s ? lp1 : lp0) + (size_t)b * (HH * WW);
        float px = kp[0], py = kp[1];
        float x = (px + 1.0f) * 0.5f * (float)(WW - 1);
        float y = (py + 1.0f) * 0.5f * (float)(HH - 1);
        float x0 = floorf(x), y0 = floorf(y);
        float wx = x - x0, wy = y - y0;
        int ix0 = (int)fminf(fmaxf(x0, 0.0f), (float)(WW - 1));
        int iy0 = (int)fminf(fmaxf(y0, 0.0f), (float)(HH - 1));
        int ix1 = (int)fminf(fmaxf(x0 + 1.0f, 0.0f), (float)(WW - 1));
        int iy1 = (int)fminf(fmaxf(y0 + 1.0f, 0.0f), (float)(HH - 1));
        float g00 = img[iy0 * WW + ix0];
        float g01 = img[iy0 * WW + ix1];
        float g10 = img[iy1 * WW + ix0];
        float g11 = img[iy1 * WW + ix1];
        float sc = g00 * (1.0f - wx) * (1.0f - wy)
                 + g01 * wx * (1.0f - wy)
                 + g10 * (1.0f - wx) * wy
                 + g11 * wx * wy;
        float xw = (px / 2.0f + 0.5f) * (float)(WW - 1);
        float yw = (py / 2.0f + 0.5f) * (float)(HH - 1);
        float sq = xw * xw + yw * yw;   // mul, mul, add — matches all d2 users
        scores[gid] = sc;
        pts[gid] = make_float4(xw, yw, sq, 0.0f);
        int imgid = gid >> 12;
        int li = gid & (NN - 1);
        int cx = (int)(xw * 0.25f); cx = cx < 0 ? 0 : (cx > CXN - 1 ? CXN - 1 : cx);
        int cy = (int)(yw * 0.25f); cy = cy < 0 ? 0 : (cy > CYN - 1 ? CYN - 1 : cy);
        int cell = imgid * NCELL + cy * CXN + cx;
        unsigned int pos = atomicAdd(&ccnt[cell], 1u);
        if (pos < SLOTS) cells[(size_t)cell * SLOTS + pos] = (unsigned short)li;
    }
    grid.sync();

    // ================= phase B: count + partner + packed rows =================
    {
        int imgid = gid >> 12;
        int li = gid & (NN - 1);
        const float4* p = pts + ((size_t)imgid << 12);
        float4 a = p[li];
        int cx = (int)(a.x * 0.25f); cx = cx < 0 ? 0 : (cx > CXN - 1 ? CXN - 1 : cx);
        int cy = (int)(a.y * 0.25f); cy = cy < 0 ? 0 : (cy > CYN - 1 ? CYN - 1 : cy);

        int c = 0, sum = 0; bool ov = false;
        unsigned long long rlo = 0ull, rhi = 0ull;
        auto place = [&](int pos, unsigned q) {
            unsigned long long v = (unsigned long long)q;
            switch (pos) {
                case 0: rlo |= v;       break;
                case 1: rlo |= v << 16; break;
                case 2: rlo |= v << 32; break;
                case 3: rlo |= v << 48; break;
                case 4: rhi |= v;       break;
                case 5: rhi |= v << 16; break;
                case 6: rhi |= v << 32; break;
                case 7: rhi |= v << 48; break;
            }
        };
        auto test = [&](unsigned q) {
            float4 qq = p[q];
            float dot = a.x * qq.x + a.y * qq.y;   // mul,mul,add (contract off)
            float t = a.z + qq.z;
            float d2 = fmaf(-2.0f, dot, t);        // == t - 2*dot (2*dot exact)
            if (d2 < RAD2) {
                if (c < 8) place(c, q);
                ++c; sum += (int)q;
            }
        };
#pragma unroll
        for (int dy = -1; dy <= 1; ++dy) {
#pragma unroll
            for (int dx = -1; dx <= 1; ++dx) {
                int yy = cy + dy, xx = cx + dx;
                bool valid = (yy >= 0) & (yy < CYN) & (xx >= 0) & (xx < CXN);
                int cell = imgid * NCELL + (valid ? yy * CXN + xx : 0);
                unsigned n = valid ? ccnt[cell] : 0u;
                if (n > SLOTS) { ov = true; n = SLOTS; }
                uint4 cl = valid ? *(const uint4*)&cells[(size_t)cell * SLOTS]
                                 : make_uint4(0, 0, 0, 0);
                unsigned q0 = cl.x & 0xffffu, q1 = cl.x >> 16;
                unsigned q2 = cl.y & 0xffffu, q3 = cl.y >> 16;
                unsigned q4 = cl.z & 0xffffu, q5 = cl.z >> 16;
                unsigned q6 = cl.w & 0xffffu, q7 = cl.w >> 16;
                if (n > 0) test(q0);
                if (n > 1) test(q1);
                if (n > 2) test(q2);
                if (n > 3) test(q3);
                if (n > 4) test(q4);
                if (n > 5) test(q5);
                if (n > 6) test(q6);
                if (n > 7) test(q7);
            }
        }
        if (ov) {   // exact fallback (cell slot overflow; ~never)
            c = 0; sum = 0; rlo = 0ull; rhi = 0ull;
            for (int j = 0; j < NN; ++j) test((unsigned)j);
        }
        cnt[gid] = (unsigned char)(c > 255 ? 255 : c);
        partner[gid] = (unsigned short)((sum - li) & 0xFFFF);  // valid iff c==2
        if (c >= 3 && c <= 8)
            rows4[gid] = make_uint4((unsigned)rlo, (unsigned)(rlo >> 32),
                                    (unsigned)rhi, (unsigned)(rhi >> 32));
    }
    grid.sync();

    // ================= phase C: NMS + reductions =================
    {
        int imgid = gid >> 12;
        int li = gid & (NN - 1);
        int base = imgid << 12;
        const float4* p = pts + (size_t)base;

        for (int t = tid; t < NN; t += 256) {
            s_sc[t] = scores[base + t];
            s_cnt[t] = cnt[base + t];
            s_partner[t] = partner[base + t];
        }
        __syncthreads();

        int c = s_cnt[li];
        bool alive = true;

        if (c >= 2) {
            int pr = s_partner[li];
            if (c == 2 && s_cnt[pr] == 2) {
                int lo = li < pr ? li : pr, hi = li < pr ? pr : li;
                int w = (s_sc[lo] >= s_sc[hi]) ? lo : hi;   // tie -> lower index
                alive = (w == li);
            } else {
                // ---- BFS component over precomputed rows ----
                unsigned short* mem = s_mem[tid];
                int cntm = 1, proc = 0;
                mem[0] = (unsigned short)li;
                auto insert = [&](unsigned q) {
                    for (int k = 0; k < cntm; ++k) if (mem[k] == (unsigned short)q) return;
                    if (cntm < CAP) mem[cntm++] = (unsigned short)q;
                };
                auto full_insert = [&](int m) {
                    float4 pm = p[m];
                    for (int j = 0; j < NN; ++j) {
                        float4 qq = p[j];
                        float dot = pm.x * qq.x + pm.y * qq.y;
                        float t = pm.z + qq.z;
                        float d2 = fmaf(-2.0f, dot, t);
                        if (d2 < RAD2) insert((unsigned)j);
                    }
                };
                while (proc < cntm) {
                    int m = mem[proc++];
                    int cm = s_cnt[m];
                    if (cm == 2) {
                        insert(s_partner[m]);
                    } else if (cm <= 8) {
                        uint4 w = rows4[base + m];
                        unsigned q0 = w.x & 0xffffu, q1 = w.x >> 16;
                        unsigned q2 = w.y & 0xffffu, q3 = w.y >> 16;
                        unsigned q4 = w.z & 0xffffu, q5 = w.z >> 16;
                        unsigned q6 = w.w & 0xffffu, q7 = w.w >> 16;
                        if (cm > 0) insert(q0);
                        if (cm > 1) insert(q1);
                        if (cm > 2) insert(q2);
                        if (cm > 3) insert(q3);
                        if (cm > 4) insert(q4);
                        if (cm > 5) insert(q5);
                        if (cm > 6) insert(q6);
                        if (cm > 7) insert(q7);
                    } else {
                        full_insert(m);
                    }
                }
                // sort members ascending
                for (int k = 1; k < cntm; ++k) {
                    unsigned short v = mem[k]; int j2 = k;
                    while (j2 > 0 && mem[j2 - 1] > v) { mem[j2] = mem[j2 - 1]; --j2; }
                    mem[j2] = v;
                }
                // ---- ascending replay (exact reference semantics) ----
                unsigned long long am = (cntm >= 64) ? ~0ull : ((1ull << cntm) - 1ull);
                auto clearbit = [&](unsigned q) {
                    for (int k = 0; k < cntm; ++k)
                        if (mem[k] == (unsigned short)q) { am &= ~(1ull << k); return; }
                };
                for (int k = 0; k < cntm; ++k) {
                    if (!((am >> k) & 1ull)) continue;
                    int m = mem[k];
                    int cm = s_cnt[m];
                    if (cm == 2) {
                        int pr2 = s_partner[m];
                        int lo = m < pr2 ? m : pr2, hi = m < pr2 ? pr2 : m;
                        int w = (s_sc[lo] >= s_sc[hi]) ? lo : hi;
                        clearbit((unsigned)(w == lo ? hi : lo));
                    } else if (cm <= 8) {
                        uint4 w = rows4[base + m];
                        unsigned q0 = w.x & 0xffffu, q1 = w.x >> 16;
                        unsigned q2 = w.y & 0xffffu, q3 = w.y >> 16;
                        unsigned q4 = w.z & 0xffffu, q5 = w.z >> 16;
                        unsigned q6 = w.w & 0xffffu, q7 = w.w >> 16;
                        float bs = -1.0f; int bi = NN;
                        auto cand = [&](int k2, unsigned q) {
                            if (k2 < cm) {
                                float s2 = s_sc[q];
                                if (s2 > bs || (s2 == bs && (int)q < bi)) { bs = s2; bi = (int)q; }
                            }
                        };
                        cand(0, q0); cand(1, q1); cand(2, q2); cand(3, q3);
                        cand(4, q4); cand(5, q5); cand(6, q6); cand(7, q7);
                        auto clr = [&](int k2, unsigned q) {
                            if (k2 < cm && (int)q != bi) clearbit(q);
                        };
                        clr(0, q0); clr(1, q1); clr(2, q2); clr(3, q3);
                        clr(4, q4); clr(5, q5); clr(6, q6); clr(7, q7);
                    } else {
                        float4 pm = p[m];
                        float bs = -1.0f; int bi = NN;
                        for (int j = 0; j < NN; ++j) {
                            float4 qq = p[j];
                            float dot = pm.x * qq.x + pm.y * qq.y;
                            float t = pm.z + qq.z;
                            float d2 = fmaf(-2.0f, dot, t);
                            if (d2 < RAD2) {
                                float s2 = s_sc[j];
                                if (s2 > bs || (s2 == bs && j < bi)) { bs = s2; bi = j; }
                            }
                        }
                        for (int j = 0; j < NN; ++j) {
                            float4 qq = p[j];
                            float dot = pm.x * qq.x + pm.y * qq.y;
                            float t = pm.z + qq.z;
                            float d2 = fmaf(-2.0f, dot, t);
                            if (d2 < RAD2 && j != bi) clearbit((unsigned)j);
                        }
                    }
                }
                for (int k = 0; k < cntm; ++k)
                    if (mem[k] == (unsigned short)li) { alive = ((am >> k) & 1ull) != 0; break; }
            }
        }

        // ---- partial sums ----
        int stream = imgid >> 2, b = imgid & 3;
        const float* disp = (stream ? dd1 : dd0) + (size_t)b * NN;
        float sum_dp = 0.f, cnt_p = 0.f, sum_sv = 0.f, cnt_v = 0.f;
        if (alive) {
            float sc = s_sc[li];
            cnt_v = 1.0f; sum_sv = sc;
            if (sc > TH_SCORE) { cnt_p = 1.0f; sum_dp = disp[li]; }
        }
        __syncthreads();
#pragma unroll
        for (int q = 0; q < 4; ++q) {
            float v = (q == 0) ? sum_dp : (q == 1) ? cnt_p : (q == 2) ? sum_sv : cnt_v;
            for (int o = 32; o > 0; o >>= 1) v += __shfl_down(v, o, 64);
            if ((tid & 63) == 0) s_red[tid >> 6] = v;
            __syncthreads();
            if (tid == 0) {
                float r = s_red[0] + s_red[1] + s_red[2] + s_red[3];
                atomicAdd(&acc[stream * 4 + q], r);
            }
            __syncthreads();
        }
    }
    grid.sync();

    // ================= finalization: block 0, thread 0 =================
    if (blockIdx.x == 0 && tid == 0) {
        float r = 0.0f;
        for (int s = 0; s < 2; ++s) {
            float sdp = acc[s * 4 + 0], cp = acc[s * 4 + 1];
            float ssv = acc[s * 4 + 2], cv = acc[s * 4 + 3];
            r += sdp / fmaxf(cp, 1.0f) + KPPEN * (ssv / fmaxf(cv, 1.0f));
        }
        out[0] = r;
    }
}

extern "C" void kernel_launch(void* const* d_in, const int* in_sizes, int n_in,
                              void* d_out, int out_size, void* d_ws, size_t ws_size,
                              hipStream_t stream)
{
    const float* lp0 = (const float*)d_in[0];
    const float* lp1 = (const float*)d_in[1];
    const float* kp0 = (const float*)d_in[2];
    const float* kp1 = (const float*)d_in[3];
    const float* dd0 = (const float*)d_in[4];
    const float* dd1 = (const float*)d_in[5];

    char* ws = (char*)d_ws;
    float*          scores  = (float*)(ws + OFF_SCORES);
    float4*         pts     = (float4*)(ws + OFF_PTS);
    unsigned char*  cnt     = (unsigned char*)(ws + OFF_CNT);
    unsigned short* partner = (unsigned short*)(ws + OFF_PARTNER);
    uint4*          rows4   = (uint4*)(ws + OFF_ROWS);
    unsigned short* cells   = (unsigned short*)(ws + OFF_CELLS);
    unsigned int*   ccnt    = (unsigned int*)(ws + OFF_CCNT);
    float*          acc     = (float*)(ws + OFF_ACC);
    float*          outp    = (float*)d_out;

    hipMemsetAsync(ws + OFF_CCNT, 0, 614432, stream);

    void* args[] = { &lp0, &lp1, &kp0, &kp1, &dd0, &dd1,
                     &scores, &pts, &cnt, &partner, &rows4,
                     &cells, &ccnt, &acc, &outp };
    hipLaunchCooperativeKernel((void*)k_fused, dim3(NBLK), dim3(256),
                               args, 0, stream);
}

// Round 11
// 141.522 us; speedup vs baseline: 1.1969x; 1.1969x over previous
//
#include <hip/hip_runtime.h>
#include <math.h>

#define NN 4096
#define HH 480
#define WW 640
#define RAD2 4.0f
#define TH_SCORE 0.1f
#define KPPEN -0.001f
#define CXN 160
#define CYN 120
#define NCELL (CXN * CYN)
#define SLOTS 8
#define CAP 48
#define RESBLK 64

// ---------------- workspace layout (bytes) ----------------
#define OFF_SCORES  0        // f32 [8][4096]               131072
#define OFF_PTS     131072   // float4 [8][4096]            524288
#define OFF_CNT     655360   // u8  [8][4096]               32768
#define OFF_PARTNER 688128   // u16 [8][4096]               65536
#define OFF_ROWS    753664   // uint4 [8][4096] (8xu16)     524288
#define OFF_CELLS   1277952  // u16 [8][19200][8]           2457600
#define OFF_CCNT    3735552  // u32 [8][19200]              614400
#define OFF_ACC     4349952  // f32 [2][4]                  32
#define OFF_DONE    4349984  // u32                         4
#define OFF_WLN     4349988  // u32                         4
#define OFF_WL      4349992  // i32 [32768]                 131072
// memset per call: [OFF_CCNT, OFF_WLN+4) = 614440 bytes (contiguous)

__global__ __launch_bounds__(256) void k_sample(
    const float* __restrict__ lp0, const float* __restrict__ lp1,
    const float* __restrict__ kp0, const float* __restrict__ kp1,
    float* __restrict__ scores, float4* __restrict__ pts,
    unsigned short* __restrict__ cells, unsigned int* __restrict__ ccnt)
{
#pragma clang fp contract(off)
    int gid = blockIdx.x * 256 + threadIdx.x;   // 0..32767
    int s = gid >> 14;
    int r = gid & 16383;
    int b = r >> 12;
    const float* kp  = (s ? kp1 : kp0) + (size_t)r * 2;
    const float* img = (s ? lp1 : lp0) + (size_t)b * (HH * WW);
    float px = kp[0], py = kp[1];
    float x = (px + 1.0f) * 0.5f * (float)(WW - 1);
    float y = (py + 1.0f) * 0.5f * (float)(HH - 1);
    float x0 = floorf(x), y0 = floorf(y);
    float wx = x - x0, wy = y - y0;
    int ix0 = (int)fminf(fmaxf(x0, 0.0f), (float)(WW - 1));
    int iy0 = (int)fminf(fmaxf(y0, 0.0f), (float)(HH - 1));
    int ix1 = (int)fminf(fmaxf(x0 + 1.0f, 0.0f), (float)(WW - 1));
    int iy1 = (int)fminf(fmaxf(y0 + 1.0f, 0.0f), (float)(HH - 1));
    float g00 = img[iy0 * WW + ix0];
    float g01 = img[iy0 * WW + ix1];
    float g10 = img[iy1 * WW + ix0];
    float g11 = img[iy1 * WW + ix1];
    float sc = g00 * (1.0f - wx) * (1.0f - wy)
             + g01 * wx * (1.0f - wy)
             + g10 * (1.0f - wx) * wy
             + g11 * wx * wy;
    float xw = (px / 2.0f + 0.5f) * (float)(WW - 1);
    float yw = (py / 2.0f + 0.5f) * (float)(HH - 1);
    float sq = xw * xw + yw * yw;   // mul, mul, add — matches all d2 users
    scores[gid] = sc;
    pts[gid] = make_float4(xw, yw, sq, 0.0f);
    int imgid = gid >> 12;
    int li = gid & (NN - 1);
    int cx = (int)(xw * 0.25f); cx = cx < 0 ? 0 : (cx > CXN - 1 ? CXN - 1 : cx);
    int cy = (int)(yw * 0.25f); cy = cy < 0 ? 0 : (cy > CYN - 1 ? CYN - 1 : cy);
    int cell = imgid * NCELL + cy * CXN + cx;
    unsigned int pos = atomicAdd(&ccnt[cell], 1u);
    if (pos < SLOTS) cells[(size_t)cell * SLOTS + pos] = (unsigned short)li;
}

// One thread per point: count, index-sum (partner), and packed 8-neighbor row.
__global__ __launch_bounds__(256) void k_cnt(
    const float4* __restrict__ pts, const unsigned short* __restrict__ cells,
    const unsigned int* __restrict__ ccnt,
    unsigned char* __restrict__ cnt, unsigned short* __restrict__ partner,
    uint4* __restrict__ rows4)
{
#pragma clang fp contract(off)
    int gid = blockIdx.x * 256 + threadIdx.x;
    int imgid = gid >> 12;
    int li = gid & (NN - 1);
    const float4* p = pts + ((size_t)imgid << 12);
    float4 a = p[li];
    int cx = (int)(a.x * 0.25f); cx = cx < 0 ? 0 : (cx > CXN - 1 ? CXN - 1 : cx);
    int cy = (int)(a.y * 0.25f); cy = cy < 0 ? 0 : (cy > CYN - 1 ? CYN - 1 : cy);

    int c = 0, sum = 0; bool ov = false;
    unsigned long long rlo = 0ull, rhi = 0ull;
    auto place = [&](int pos, unsigned q) {
        unsigned long long v = (unsigned long long)q;
        switch (pos) {
            case 0: rlo |= v;       break;
            case 1: rlo |= v << 16; break;
            case 2: rlo |= v << 32; break;
            case 3: rlo |= v << 48; break;
            case 4: rhi |= v;       break;
            case 5: rhi |= v << 16; break;
            case 6: rhi |= v << 32; break;
            case 7: rhi |= v << 48; break;
        }
    };
    auto test = [&](unsigned q) {
        float4 qq = p[q];
        float dot = a.x * qq.x + a.y * qq.y;   // mul,mul,add (contract off)
        float t = a.z + qq.z;
        float d2 = fmaf(-2.0f, dot, t);        // == t - 2*dot (2*dot exact)
        if (d2 < RAD2) {
            if (c < 8) place(c, q);
            ++c; sum += (int)q;
        }
    };
#pragma unroll
    for (int dy = -1; dy <= 1; ++dy) {
#pragma unroll
        for (int dx = -1; dx <= 1; ++dx) {
            int yy = cy + dy, xx = cx + dx;
            bool valid = (yy >= 0) & (yy < CYN) & (xx >= 0) & (xx < CXN);
            int cell = imgid * NCELL + (valid ? yy * CXN + xx : 0);
            unsigned n = valid ? ccnt[cell] : 0u;
            if (n > SLOTS) { ov = true; n = SLOTS; }
            uint4 cl = valid ? *(const uint4*)&cells[(size_t)cell * SLOTS]
                             : make_uint4(0, 0, 0, 0);
            unsigned q0 = cl.x & 0xffffu, q1 = cl.x >> 16;
            unsigned q2 = cl.y & 0xffffu, q3 = cl.y >> 16;
            unsigned q4 = cl.z & 0xffffu, q5 = cl.z >> 16;
            unsigned q6 = cl.w & 0xffffu, q7 = cl.w >> 16;
            if (n > 0) test(q0);
            if (n > 1) test(q1);
            if (n > 2) test(q2);
            if (n > 3) test(q3);
            if (n > 4) test(q4);
            if (n > 5) test(q5);
            if (n > 6) test(q6);
            if (n > 7) test(q7);
        }
    }
    if (ov) {   // exact fallback (cell slot overflow; ~never)
        c = 0; sum = 0; rlo = 0ull; rhi = 0ull;
        for (int j = 0; j < NN; ++j) test((unsigned)j);
    }
    cnt[gid] = (unsigned char)(c > 255 ? 255 : c);
    partner[gid] = (unsigned short)((sum - li) & 0xFFFF);  // valid iff c==2
    if (c >= 3 && c <= 8)
        rows4[gid] = make_uint4((unsigned)rlo, (unsigned)(rlo >> 32),
                                (unsigned)rhi, (unsigned)(rhi >> 32));
}

// Fast pass: per-point O(1). Pairs resolved inline; residual points enqueued
// (their contribution is added by k_res). No whole-image staging.
__global__ __launch_bounds__(256) void k_nms(
    const float* __restrict__ scoresG, const unsigned char* __restrict__ cntG,
    const unsigned short* __restrict__ partnerG,
    const float* __restrict__ dd0, const float* __restrict__ dd1,
    unsigned int* __restrict__ wl_n, int* __restrict__ wl,
    float* __restrict__ acc)
{
    __shared__ float s_red[4];
    int tid = threadIdx.x;
    int gid = blockIdx.x * 256 + tid;
    int imgid = gid >> 12;
    int li = gid & (NN - 1);
    int base = imgid << 12;

    int c = cntG[gid];
    bool alive = true, residual = false;
    if (c >= 3) {
        residual = true;
    } else if (c == 2) {
        int pr = partnerG[gid];
        if (cntG[base + pr] == 2) {
            float sl = scoresG[gid], sp = scoresG[base + pr];
            int lo = li < pr ? li : pr, hi = li < pr ? pr : li;
            float slo = li < pr ? sl : sp, shi = li < pr ? sp : sl;
            int w = (slo >= shi) ? lo : hi;   // tie -> lower index
            alive = (w == li);
        } else {
            residual = true;
        }
    }
    if (residual) {
        unsigned pos = atomicAdd(wl_n, 1u);
        wl[pos] = gid;
    }

    // contributions for non-residual points only (block is within one image)
    int stream = imgid >> 2, b = imgid & 3;
    const float* disp = (stream ? dd1 : dd0) + (size_t)b * NN;
    float sum_dp = 0.f, cnt_p = 0.f, sum_sv = 0.f, cnt_v = 0.f;
    if (!residual && alive) {
        float sc = scoresG[gid];
        cnt_v = 1.0f; sum_sv = sc;
        if (sc > TH_SCORE) { cnt_p = 1.0f; sum_dp = disp[li]; }
    }
    __syncthreads();
#pragma unroll
    for (int q = 0; q < 4; ++q) {
        float v = (q == 0) ? sum_dp : (q == 1) ? cnt_p : (q == 2) ? sum_sv : cnt_v;
        for (int o = 32; o > 0; o >>= 1) v += __shfl_down(v, o, 64);
        if ((tid & 63) == 0) s_red[tid >> 6] = v;
        __syncthreads();
        if (tid == 0) {
            float r = s_red[0] + s_red[1] + s_red[2] + s_red[3];
            atomicAdd(&acc[stream * 4 + q], r);
        }
        __syncthreads();
    }
}

// Residual pass: one lane per worklist item; private BFS + ascending replay
// (exact reference semantics). ~1200 items -> all BFS in parallel lanes;
// critical path = one BFS. Finalization via done-counter (R7-verified).
__global__ __launch_bounds__(RESBLK) void k_res(
    const float* __restrict__ scoresG, const float4* __restrict__ pts,
    const unsigned char* __restrict__ cntG, const unsigned short* __restrict__ partnerG,
    const uint4* __restrict__ rows4,
    const float* __restrict__ dd0, const float* __restrict__ dd1,
    const unsigned int* __restrict__ wl_n, const int* __restrict__ wl,
    float* __restrict__ acc, unsigned int* __restrict__ done,
    float* __restrict__ out)
{
#pragma clang fp contract(off)
    __shared__ unsigned short s_mem[RESBLK][CAP + 2];   // 6.5 KB
    int tid = threadIdx.x;
    int n = (int)*wl_n;
    float a_dp = 0.f, a_cp = 0.f, a_sv = 0.f, a_cv = 0.f;   // stream 0
    float b_dp = 0.f, b_cp = 0.f, b_sv = 0.f, b_cv = 0.f;   // stream 1

    for (int t = blockIdx.x * RESBLK + tid; t < n; t += gridDim.x * RESBLK) {
        int gid = wl[t];
        int imgid = gid >> 12;
        int li = gid & (NN - 1);
        int base = imgid << 12;
        const float4* p = pts + (size_t)base;

        // ---- BFS component over precomputed rows ----
        unsigned short* mem = s_mem[tid];
        int cntm = 1, proc = 0;
        mem[0] = (unsigned short)li;
        auto insert = [&](unsigned q) {
            for (int k = 0; k < cntm; ++k) if (mem[k] == (unsigned short)q) return;
            if (cntm < CAP) mem[cntm++] = (unsigned short)q;
        };
        auto full_insert = [&](int m) {
            float4 pm = p[m];
            for (int j = 0; j < NN; ++j) {
                float4 qq = p[j];
                float dot = pm.x * qq.x + pm.y * qq.y;
                float tt = pm.z + qq.z;
                float d2 = fmaf(-2.0f, dot, tt);
                if (d2 < RAD2) insert((unsigned)j);
            }
        };
        while (proc < cntm) {
            int m = mem[proc++];
            int cm = cntG[base + m];
            if (cm == 2) {
                insert(partnerG[base + m]);
            } else if (cm <= 8) {
                uint4 w = rows4[base + m];
                unsigned q0 = w.x & 0xffffu, q1 = w.x >> 16;
                unsigned q2 = w.y & 0xffffu, q3 = w.y >> 16;
                unsigned q4 = w.z & 0xffffu, q5 = w.z >> 16;
                unsigned q6 = w.w & 0xffffu, q7 = w.w >> 16;
                if (cm > 0) insert(q0);
                if (cm > 1) insert(q1);
                if (cm > 2) insert(q2);
                if (cm > 3) insert(q3);
                if (cm > 4) insert(q4);
                if (cm > 5) insert(q5);
                if (cm > 6) insert(q6);
                if (cm > 7) insert(q7);
            } else {
                full_insert(m);
            }
        }
        // sort members ascending
        for (int k = 1; k < cntm; ++k) {
            unsigned short v = mem[k]; int j2 = k;
            while (j2 > 0 && mem[j2 - 1] > v) { mem[j2] = mem[j2 - 1]; --j2; }
            mem[j2] = v;
        }
        // ---- ascending replay (exact reference semantics) ----
        unsigned long long am = (cntm >= 64) ? ~0ull : ((1ull << cntm) - 1ull);
        auto clearbit = [&](unsigned q) {
            for (int k = 0; k < cntm; ++k)
                if (mem[k] == (unsigned short)q) { am &= ~(1ull << k); return; }
        };
        for (int k = 0; k < cntm; ++k) {
            if (!((am >> k) & 1ull)) continue;
            int m = mem[k];
            int cm = cntG[base + m];
            if (cm == 2) {
                int pr2 = partnerG[base + m];
                int lo = m < pr2 ? m : pr2, hi = m < pr2 ? pr2 : m;
                float slo = scoresG[base + lo], shi = scoresG[base + hi];
                int w = (slo >= shi) ? lo : hi;
                clearbit((unsigned)(w == lo ? hi : lo));
            } else if (cm <= 8) {
                uint4 w = rows4[base + m];
                unsigned q0 = w.x & 0xffffu, q1 = w.x >> 16;
                unsigned q2 = w.y & 0xffffu, q3 = w.y >> 16;
                unsigned q4 = w.z & 0xffffu, q5 = w.z >> 16;
                unsigned q6 = w.w & 0xffffu, q7 = w.w >> 16;
                float bs = -1.0f; int bi = NN;
                auto cand = [&](int k2, unsigned q) {
                    if (k2 < cm) {
                        float s2 = scoresG[base + q];
                        if (s2 > bs || (s2 == bs && (int)q < bi)) { bs = s2; bi = (int)q; }
                    }
                };
                cand(0, q0); cand(1, q1); cand(2, q2); cand(3, q3);
                cand(4, q4); cand(5, q5); cand(6, q6); cand(7, q7);
                auto clr = [&](int k2, unsigned q) {
                    if (k2 < cm && (int)q != bi) clearbit(q);
                };
                clr(0, q0); clr(1, q1); clr(2, q2); clr(3, q3);
                clr(4, q4); clr(5, q5); clr(6, q6); clr(7, q7);
            } else {
                float4 pm = p[m];
                float bs = -1.0f; int bi = NN;
                for (int j = 0; j < NN; ++j) {
                    float4 qq = p[j];
                    float dot = pm.x * qq.x + pm.y * qq.y;
                    float tt = pm.z + qq.z;
                    float d2 = fmaf(-2.0f, dot, tt);
                    if (d2 < RAD2) {
                        float s2 = scoresG[base + j];
                        if (s2 > bs || (s2 == bs && j < bi)) { bs = s2; bi = j; }
                    }
                }
                for (int j = 0; j < NN; ++j) {
                    float4 qq = p[j];
                    float dot = pm.x * qq.x + pm.y * qq.y;
                    float tt = pm.z + qq.z;
                    float d2 = fmaf(-2.0f, dot, tt);
                    if (d2 < RAD2 && j != bi) clearbit((unsigned)j);
                }
            }
        }
        bool alive = false;
        for (int k = 0; k < cntm; ++k)
            if (mem[k] == (unsigned short)li) { alive = ((am >> k) & 1ull) != 0; break; }

        if (alive) {
            float sc = scoresG[gid];
            int stream = imgid >> 2, b = imgid & 3;
            const float* disp = (stream ? dd1 : dd0) + (size_t)b * NN;
            float dp = 0.f, cp = 0.f;
            if (sc > TH_SCORE) { dp = disp[li]; cp = 1.0f; }
            if (stream == 0) { a_sv += sc; a_cv += 1.0f; a_dp += dp; a_cp += cp; }
            else             { b_sv += sc; b_cv += 1.0f; b_dp += dp; b_cp += cp; }
        }
    }

    // wave-reduce the 8 accumulators (block = 1 wave), one atomic each
    auto wred = [&](float v) {
        for (int o = 32; o > 0; o >>= 1) v += __shfl_down(v, o, 64);
        return v;
    };
    a_dp = wred(a_dp); a_cp = wred(a_cp); a_sv = wred(a_sv); a_cv = wred(a_cv);
    b_dp = wred(b_dp); b_cp = wred(b_cp); b_sv = wred(b_sv); b_cv = wred(b_cv);
    if (tid == 0) {
        atomicAdd(&acc[0], a_dp); atomicAdd(&acc[1], a_cp);
        atomicAdd(&acc[2], a_sv); atomicAdd(&acc[3], a_cv);
        atomicAdd(&acc[4], b_dp); atomicAdd(&acc[5], b_cp);
        atomicAdd(&acc[6], b_sv); atomicAdd(&acc[7], b_cv);
    }

    // ---- fused finalization: last block computes the scalar ----
    if (tid == 0) {
        __threadfence();
        unsigned prev = atomicAdd(done, 1u);
        if (prev == gridDim.x - 1) {
            float r = 0.0f;
            for (int s = 0; s < 2; ++s) {
                float sdp = atomicAdd(&acc[s * 4 + 0], 0.0f);
                float cp  = atomicAdd(&acc[s * 4 + 1], 0.0f);
                float ssv = atomicAdd(&acc[s * 4 + 2], 0.0f);
                float cv  = atomicAdd(&acc[s * 4 + 3], 0.0f);
                r += sdp / fmaxf(cp, 1.0f) + KPPEN * (ssv / fmaxf(cv, 1.0f));
            }
            out[0] = r;
        }
    }
}

extern "C" void kernel_launch(void* const* d_in, const int* in_sizes, int n_in,
                              void* d_out, int out_size, void* d_ws, size_t ws_size,
                              hipStream_t stream)
{
    const float* lp0 = (const float*)d_in[0];
    const float* lp1 = (const float*)d_in[1];
    const float* kp0 = (const float*)d_in[2];
    const float* kp1 = (const float*)d_in[3];
    const float* dd0 = (const float*)d_in[4];
    const float* dd1 = (const float*)d_in[5];

    char* ws = (char*)d_ws;
    float*          scores  = (float*)(ws + OFF_SCORES);
    float4*         pts     = (float4*)(ws + OFF_PTS);
    unsigned char*  cnt     = (unsigned char*)(ws + OFF_CNT);
    unsigned short* partner = (unsigned short*)(ws + OFF_PARTNER);
    uint4*          rows4   = (uint4*)(ws + OFF_ROWS);
    unsigned short* cells   = (unsigned short*)(ws + OFF_CELLS);
    unsigned int*   ccnt    = (unsigned int*)(ws + OFF_CCNT);
    float*          acc     = (float*)(ws + OFF_ACC);
    unsigned int*   done    = (unsigned int*)(ws + OFF_DONE);
    unsigned int*   wl_n    = (unsigned int*)(ws + OFF_WLN);
    int*            wl      = (int*)(ws + OFF_WL);

    hipMemsetAsync(ws + OFF_CCNT, 0, 614440, stream);
    k_sample<<<128, 256, 0, stream>>>(lp0, lp1, kp0, kp1, scores, pts, cells, ccnt);
    k_cnt<<<128, 256, 0, stream>>>(pts, cells, ccnt, cnt, partner, rows4);
    k_nms<<<128, 256, 0, stream>>>(scores, cnt, partner, dd0, dd1, wl_n, wl, acc);
    k_res<<<64, RESBLK, 0, stream>>>(scores, pts, cnt, partner, rows4,
                                     dd0, dd1, wl_n, wl, acc, done,
                                     (float*)d_out);
}

// Round 12
// 126.546 us; speedup vs baseline: 1.3385x; 1.1183x over previous
//
#include <hip/hip_runtime.h>
#include <math.h>

#define NN 4096
#define HH 480
#define WW 640
#define RAD2 4.0f
#define TH_SCORE 0.1f
#define KPPEN -0.001f
#define CXN 160
#define CYN 120
#define NCELL (CXN * CYN)
#define SLOTS 8
#define CAP 38
#define ROWCAP 256
#define IMGB 4                 // NMS blocks per image
#define NBLK2 (8 * IMGB)       // 32

// ---------------- workspace layout (bytes) ----------------
#define OFF_SCORES  0        // f32 [8][4096]               131072
#define OFF_PTS     131072   // float4 [8][4096]            524288
#define OFF_CNT     655360   // u8  [8][4096]               32768
#define OFF_PARTNER 688128   // u16 [8][4096]               65536
#define OFF_ROWS    753664   // uint4 [8][4096] (8xu16)     524288
#define OFF_CELLS   1277952  // u16 [8][19200][8]           2457600
#define OFF_CCNT    3735552  // u32 [8][19200]              614400
#define OFF_ACC     4349952  // f32 [2][4]                  32
#define OFF_DONE    4349984  // u32                         4
// memset per call: [OFF_CCNT, OFF_DONE+4) = 614436 bytes (contiguous)

__global__ __launch_bounds__(256) void k_sample(
    const float* __restrict__ lp0, const float* __restrict__ lp1,
    const float* __restrict__ kp0, const float* __restrict__ kp1,
    float* __restrict__ scores, float4* __restrict__ pts,
    unsigned short* __restrict__ cells, unsigned int* __restrict__ ccnt)
{
#pragma clang fp contract(off)
    int gid = blockIdx.x * 256 + threadIdx.x;   // 0..32767
    int s = gid >> 14;
    int r = gid & 16383;
    int b = r >> 12;
    const float* kp  = (s ? kp1 : kp0) + (size_t)r * 2;
    const float* img = (s ? lp1 : lp0) + (size_t)b * (HH * WW);
    float px = kp[0], py = kp[1];
    float x = (px + 1.0f) * 0.5f * (float)(WW - 1);
    float y = (py + 1.0f) * 0.5f * (float)(HH - 1);
    float x0 = floorf(x), y0 = floorf(y);
    float wx = x - x0, wy = y - y0;
    int ix0 = (int)fminf(fmaxf(x0, 0.0f), (float)(WW - 1));
    int iy0 = (int)fminf(fmaxf(y0, 0.0f), (float)(HH - 1));
    int ix1 = (int)fminf(fmaxf(x0 + 1.0f, 0.0f), (float)(WW - 1));
    int iy1 = (int)fminf(fmaxf(y0 + 1.0f, 0.0f), (float)(HH - 1));
    float g00 = img[iy0 * WW + ix0];
    float g01 = img[iy0 * WW + ix1];
    float g10 = img[iy1 * WW + ix0];
    float g11 = img[iy1 * WW + ix1];
    float sc = g00 * (1.0f - wx) * (1.0f - wy)
             + g01 * wx * (1.0f - wy)
             + g10 * (1.0f - wx) * wy
             + g11 * wx * wy;
    float xw = (px / 2.0f + 0.5f) * (float)(WW - 1);
    float yw = (py / 2.0f + 0.5f) * (float)(HH - 1);
    float sq = xw * xw + yw * yw;   // mul, mul, add — matches all d2 users
    scores[gid] = sc;
    pts[gid] = make_float4(xw, yw, sq, 0.0f);
    int imgid = gid >> 12;
    int li = gid & (NN - 1);
    int cx = (int)(xw * 0.25f); cx = cx < 0 ? 0 : (cx > CXN - 1 ? CXN - 1 : cx);
    int cy = (int)(yw * 0.25f); cy = cy < 0 ? 0 : (cy > CYN - 1 ? CYN - 1 : cy);
    int cell = imgid * NCELL + cy * CXN + cx;
    unsigned int pos = atomicAdd(&ccnt[cell], 1u);
    if (pos < SLOTS) cells[(size_t)cell * SLOTS + pos] = (unsigned short)li;
}

// One thread per point: count, index-sum (partner), and packed 8-neighbor row.
__global__ __launch_bounds__(256) void k_cnt(
    const float4* __restrict__ pts, const unsigned short* __restrict__ cells,
    const unsigned int* __restrict__ ccnt,
    unsigned char* __restrict__ cnt, unsigned short* __restrict__ partner,
    uint4* __restrict__ rows4)
{
#pragma clang fp contract(off)
    int gid = blockIdx.x * 256 + threadIdx.x;
    int imgid = gid >> 12;
    int li = gid & (NN - 1);
    const float4* p = pts + ((size_t)imgid << 12);
    float4 a = p[li];
    int cx = (int)(a.x * 0.25f); cx = cx < 0 ? 0 : (cx > CXN - 1 ? CXN - 1 : cx);
    int cy = (int)(a.y * 0.25f); cy = cy < 0 ? 0 : (cy > CYN - 1 ? CYN - 1 : cy);

    int c = 0, sum = 0; bool ov = false;
    unsigned long long rlo = 0ull, rhi = 0ull;
    auto place = [&](int pos, unsigned q) {
        unsigned long long v = (unsigned long long)q;
        switch (pos) {
            case 0: rlo |= v;       break;
            case 1: rlo |= v << 16; break;
            case 2: rlo |= v << 32; break;
            case 3: rlo |= v << 48; break;
            case 4: rhi |= v;       break;
            case 5: rhi |= v << 16; break;
            case 6: rhi |= v << 32; break;
            case 7: rhi |= v << 48; break;
        }
    };
    auto test = [&](unsigned q) {
        float4 qq = p[q];
        float dot = a.x * qq.x + a.y * qq.y;   // mul,mul,add (contract off)
        float t = a.z + qq.z;
        float d2 = fmaf(-2.0f, dot, t);        // == t - 2*dot (2*dot exact)
        if (d2 < RAD2) {
            if (c < 8) place(c, q);
            ++c; sum += (int)q;
        }
    };
#pragma unroll
    for (int dy = -1; dy <= 1; ++dy) {
#pragma unroll
        for (int dx = -1; dx <= 1; ++dx) {
            int yy = cy + dy, xx = cx + dx;
            bool valid = (yy >= 0) & (yy < CYN) & (xx >= 0) & (xx < CXN);
            int cell = imgid * NCELL + (valid ? yy * CXN + xx : 0);
            unsigned n = valid ? ccnt[cell] : 0u;
            if (n > SLOTS) { ov = true; n = SLOTS; }
            uint4 cl = valid ? *(const uint4*)&cells[(size_t)cell * SLOTS]
                             : make_uint4(0, 0, 0, 0);
            unsigned q0 = cl.x & 0xffffu, q1 = cl.x >> 16;
            unsigned q2 = cl.y & 0xffffu, q3 = cl.y >> 16;
            unsigned q4 = cl.z & 0xffffu, q5 = cl.z >> 16;
            unsigned q6 = cl.w & 0xffffu, q7 = cl.w >> 16;
            if (n > 0) test(q0);
            if (n > 1) test(q1);
            if (n > 2) test(q2);
            if (n > 3) test(q3);
            if (n > 4) test(q4);
            if (n > 5) test(q5);
            if (n > 6) test(q6);
            if (n > 7) test(q7);
        }
    }
    if (ov) {   // exact fallback (cell slot overflow; ~never)
        c = 0; sum = 0; rlo = 0ull; rhi = 0ull;
        for (int j = 0; j < NN; ++j) test((unsigned)j);
    }
    cnt[gid] = (unsigned char)(c > 255 ? 255 : c);
    partner[gid] = (unsigned short)((sum - li) & 0xFFFF);  // valid iff c==2
    if (c >= 3 && c <= 8)
        rows4[gid] = make_uint4((unsigned)rlo, (unsigned)(rlo >> 32),
                                (unsigned)rhi, (unsigned)(rhi >> 32));
}

// NMS: 4 blocks per image. Full-image tables + compacted rows ALL in LDS,
// so the per-lane BFS+replay never touches global memory. Pairs O(1) inline;
// residual worklist per segment; done-counter finalization.
__global__ __launch_bounds__(256) void k_nms(
    const float* __restrict__ scoresG, const float4* __restrict__ pts,
    const unsigned char* __restrict__ cntG, const unsigned short* __restrict__ partnerG,
    const uint4* __restrict__ rows4,
    const float* __restrict__ dd0, const float* __restrict__ dd1,
    float* __restrict__ acc, unsigned int* __restrict__ done,
    float* __restrict__ out)
{
#pragma clang fp contract(off)
    __shared__ float          s_sc[NN];            // 16 KB
    __shared__ unsigned char  s_cnt[NN];           // 4 KB
    __shared__ unsigned char  s_alive[NN];         // 4 KB
    __shared__ unsigned char  s_rowidx[NN];        // 4 KB
    __shared__ unsigned short s_partner[NN];       // 8 KB
    __shared__ uint4          s_rows[ROWCAP];      // 4 KB
    __shared__ unsigned short s_wl[1024];          // 2 KB
    __shared__ unsigned short s_mem[256][CAP + 2]; // 20 KB
    __shared__ int s_nrows, s_wln;
    __shared__ float s_red[4];

    int blk = blockIdx.x;
    int imgid = blk >> 2;          // / IMGB
    int sub = blk & (IMGB - 1);
    int base = imgid << 12;
    int tid = threadIdx.x;
    const float4* p = pts + (size_t)base;

    if (tid == 0) { s_nrows = 0; s_wln = 0; }
    for (int t = tid; t < NN; t += 256) {
        s_sc[t] = scoresG[base + t];
        s_cnt[t] = cntG[base + t];
        s_partner[t] = partnerG[base + t];
        s_alive[t] = 1;
        s_rowidx[t] = 255;
    }
    __syncthreads();

    // ---- compact rows of all cnt[3..8] points into LDS ----
    for (int t = tid; t < NN; t += 256) {
        int c = s_cnt[t];
        if (c >= 3 && c <= 8) {
            int slot = atomicAdd(&s_nrows, 1);
            if (slot < ROWCAP) {
                s_rowidx[t] = (unsigned char)slot;
                s_rows[slot] = rows4[base + t];
            }
        }
    }

    // ---- classify own 1024-point segment: pairs inline, residual -> wl ----
    int segbase = sub << 10;
#pragma unroll
    for (int k = 0; k < 4; ++k) {
        int li = segbase + (k << 8) + tid;
        int c = s_cnt[li];
        if (c >= 3) {
            int pos = atomicAdd(&s_wln, 1);
            s_wl[pos] = (unsigned short)li;
        } else if (c == 2) {
            int pr = s_partner[li];
            if (s_cnt[pr] == 2) {
                int lo = li < pr ? li : pr, hi = li < pr ? pr : li;
                int w = (s_sc[lo] >= s_sc[hi]) ? lo : hi;   // tie -> lower index
                s_alive[li] = (w == li) ? 1 : 0;
            } else {
                int pos = atomicAdd(&s_wln, 1);
                s_wl[pos] = (unsigned short)li;
            }
        }
    }
    __syncthreads();
    int wln = s_wln;

    // ---- per-lane BFS + ascending replay, all-LDS (exact ref semantics) ----
    for (int t = tid; t < wln; t += 256) {
        int li = s_wl[t];
        unsigned short* mem = s_mem[tid];
        int cntm = 1, proc = 0;
        mem[0] = (unsigned short)li;
        auto insert = [&](unsigned q) {
            for (int k = 0; k < cntm; ++k) if (mem[k] == (unsigned short)q) return;
            if (cntm < CAP) mem[cntm++] = (unsigned short)q;
        };
        auto getrow = [&](int m) -> uint4 {
            int idx = s_rowidx[m];
            return (idx != 255) ? s_rows[idx] : rows4[base + m];
        };
        auto full_insert = [&](int m) {   // cnt>8 fallback (~never)
            float4 pm = p[m];
            for (int j = 0; j < NN; ++j) {
                float4 qq = p[j];
                float dot = pm.x * qq.x + pm.y * qq.y;
                float tt = pm.z + qq.z;
                float d2 = fmaf(-2.0f, dot, tt);
                if (d2 < RAD2) insert((unsigned)j);
            }
        };
        while (proc < cntm) {
            int m = mem[proc++];
            int cm = s_cnt[m];
            if (cm == 2) {
                insert(s_partner[m]);
            } else if (cm <= 8) {
                uint4 w = getrow(m);
                unsigned q0 = w.x & 0xffffu, q1 = w.x >> 16;
                unsigned q2 = w.y & 0xffffu, q3 = w.y >> 16;
                unsigned q4 = w.z & 0xffffu, q5 = w.z >> 16;
                unsigned q6 = w.w & 0xffffu, q7 = w.w >> 16;
                if (cm > 0) insert(q0);
                if (cm > 1) insert(q1);
                if (cm > 2) insert(q2);
                if (cm > 3) insert(q3);
                if (cm > 4) insert(q4);
                if (cm > 5) insert(q5);
                if (cm > 6) insert(q6);
                if (cm > 7) insert(q7);
            } else {
                full_insert(m);
            }
        }
        // sort members ascending
        for (int k = 1; k < cntm; ++k) {
            unsigned short v = mem[k]; int j2 = k;
            while (j2 > 0 && mem[j2 - 1] > v) { mem[j2] = mem[j2 - 1]; --j2; }
            mem[j2] = v;
        }
        // ascending replay
        unsigned long long am = (cntm >= 64) ? ~0ull : ((1ull << cntm) - 1ull);
        auto clearbit = [&](unsigned q) {
            for (int k = 0; k < cntm; ++k)
                if (mem[k] == (unsigned short)q) { am &= ~(1ull << k); return; }
        };
        for (int k = 0; k < cntm; ++k) {
            if (!((am >> k) & 1ull)) continue;
            int m = mem[k];
            int cm = s_cnt[m];
            if (cm == 2) {
                int pr2 = s_partner[m];
                int lo = m < pr2 ? m : pr2, hi = m < pr2 ? pr2 : m;
                int w = (s_sc[lo] >= s_sc[hi]) ? lo : hi;
                clearbit((unsigned)(w == lo ? hi : lo));
            } else if (cm <= 8) {
                uint4 w = getrow(m);
                unsigned q0 = w.x & 0xffffu, q1 = w.x >> 16;
                unsigned q2 = w.y & 0xffffu, q3 = w.y >> 16;
                unsigned q4 = w.z & 0xffffu, q5 = w.z >> 16;
                unsigned q6 = w.w & 0xffffu, q7 = w.w >> 16;
                float bs = -1.0f; int bi = NN;
                auto cand = [&](int k2, unsigned q) {
                    if (k2 < cm) {
                        float s2 = s_sc[q];
                        if (s2 > bs || (s2 == bs && (int)q < bi)) { bs = s2; bi = (int)q; }
                    }
                };
                cand(0, q0); cand(1, q1); cand(2, q2); cand(3, q3);
                cand(4, q4); cand(5, q5); cand(6, q6); cand(7, q7);
                auto clr = [&](int k2, unsigned q) {
                    if (k2 < cm && (int)q != bi) clearbit(q);
                };
                clr(0, q0); clr(1, q1); clr(2, q2); clr(3, q3);
                clr(4, q4); clr(5, q5); clr(6, q6); clr(7, q7);
            } else {
                float4 pm = p[m];
                float bs = -1.0f; int bi = NN;
                for (int j = 0; j < NN; ++j) {
                    float4 qq = p[j];
                    float dot = pm.x * qq.x + pm.y * qq.y;
                    float tt = pm.z + qq.z;
                    float d2 = fmaf(-2.0f, dot, tt);
                    if (d2 < RAD2) {
                        float s2 = s_sc[j];
                        if (s2 > bs || (s2 == bs && j < bi)) { bs = s2; bi = j; }
                    }
                }
                for (int j = 0; j < NN; ++j) {
                    float4 qq = p[j];
                    float dot = pm.x * qq.x + pm.y * qq.y;
                    float tt = pm.z + qq.z;
                    float d2 = fmaf(-2.0f, dot, tt);
                    if (d2 < RAD2 && j != bi) clearbit((unsigned)j);
                }
            }
        }
        bool alive = false;
        for (int k = 0; k < cntm; ++k)
            if (mem[k] == (unsigned short)li) { alive = ((am >> k) & 1ull) != 0; break; }
        s_alive[li] = alive ? 1 : 0;
    }
    __syncthreads();

    // ---- reduce own segment ----
    int stream = imgid >> 2, b = imgid & 3;
    const float* disp = (stream ? dd1 : dd0) + (size_t)b * NN;
    float sum_dp = 0.f, cnt_p = 0.f, sum_sv = 0.f, cnt_v = 0.f;
#pragma unroll
    for (int k = 0; k < 4; ++k) {
        int li = segbase + (k << 8) + tid;
        if (s_alive[li]) {
            float sc = s_sc[li];
            cnt_v += 1.0f; sum_sv += sc;
            if (sc > TH_SCORE) { cnt_p += 1.0f; sum_dp += disp[li]; }
        }
    }
#pragma unroll
    for (int q = 0; q < 4; ++q) {
        float v = (q == 0) ? sum_dp : (q == 1) ? cnt_p : (q == 2) ? sum_sv : cnt_v;
        for (int o = 32; o > 0; o >>= 1) v += __shfl_down(v, o, 64);
        if ((tid & 63) == 0) s_red[tid >> 6] = v;
        __syncthreads();
        if (tid == 0) {
            float r = s_red[0] + s_red[1] + s_red[2] + s_red[3];
            atomicAdd(&acc[stream * 4 + q], r);
        }
        __syncthreads();
    }

    // ---- fused finalization: last of NBLK2 blocks computes the scalar ----
    if (tid == 0) {
        __threadfence();
        unsigned prev = atomicAdd(done, 1u);
        if (prev == NBLK2 - 1u) {
            float r = 0.0f;
            for (int s = 0; s < 2; ++s) {
                float sdp = atomicAdd(&acc[s * 4 + 0], 0.0f);
                float cp  = atomicAdd(&acc[s * 4 + 1], 0.0f);
                float ssv = atomicAdd(&acc[s * 4 + 2], 0.0f);
                float cv  = atomicAdd(&acc[s * 4 + 3], 0.0f);
                r += sdp / fmaxf(cp, 1.0f) + KPPEN * (ssv / fmaxf(cv, 1.0f));
            }
            out[0] = r;
        }
    }
}

extern "C" void kernel_launch(void* const* d_in, const int* in_sizes, int n_in,
                              void* d_out, int out_size, void* d_ws, size_t ws_size,
                              hipStream_t stream)
{
    const float* lp0 = (const float*)d_in[0];
    const float* lp1 = (const float*)d_in[1];
    const float* kp0 = (const float*)d_in[2];
    const float* kp1 = (const float*)d_in[3];
    const float* dd0 = (const float*)d_in[4];
    const float* dd1 = (const float*)d_in[5];

    char* ws = (char*)d_ws;
    float*          scores  = (float*)(ws + OFF_SCORES);
    float4*         pts     = (float4*)(ws + OFF_PTS);
    unsigned char*  cnt     = (unsigned char*)(ws + OFF_CNT);
    unsigned short* partner = (unsigned short*)(ws + OFF_PARTNER);
    uint4*          rows4   = (uint4*)(ws + OFF_ROWS);
    unsigned short* cells   = (unsigned short*)(ws + OFF_CELLS);
    unsigned int*   ccnt    = (unsigned int*)(ws + OFF_CCNT);
    float*          acc     = (float*)(ws + OFF_ACC);
    unsigned int*   done    = (unsigned int*)(ws + OFF_DONE);

    hipMemsetAsync(ws + OFF_CCNT, 0, 614436, stream);
    k_sample<<<128, 256, 0, stream>>>(lp0, lp1, kp0, kp1, scores, pts, cells, ccnt);
    k_cnt<<<128, 256, 0, stream>>>(pts, cells, ccnt, cnt, partner, rows4);
    k_nms<<<NBLK2, 256, 0, stream>>>(scores, pts, cnt, partner, rows4,
                                     dd0, dd1, acc, done, (float*)d_out);
}